// Round 8
// baseline (123.412 us; speedup 1.0000x reference)
//
#include <hip/hip_runtime.h>
#include <hip/hip_cooperative_groups.h>

namespace cg = cooperative_groups;

// Problem constants: B=256, P=64, D=1024, MARGIN=0.1
constexpr int NB = 256;
constexpr int NP = 64;
constexpr int ND = 1024;
constexpr float MARGIN = 0.1f;

typedef __attribute__((ext_vector_type(8))) short bf16x8;  // 8 bf16 (4 VGPRs)
typedef __attribute__((ext_vector_type(4))) short bf16x4;  // 4 bf16 (2 VGPRs)
typedef __attribute__((ext_vector_type(4))) float f32x4;   // MFMA accumulator

// fp32 -> bf16 round-to-nearest-even (inputs are finite gaussians; no NaN path)
static __device__ inline unsigned short f2bf(float f) {
  unsigned u = __builtin_bit_cast(unsigned, f);
  u += 0x7fffu + ((u >> 16) & 1u);
  return (unsigned short)(u >> 16);
}

static __device__ inline bf16x4 cvt4(float4 a) {
  bf16x4 r;
  r[0] = (short)f2bf(a.x); r[1] = (short)f2bf(a.y);
  r[2] = (short)f2bf(a.z); r[3] = (short)f2bf(a.w);
  return r;
}

// ---------------------------------------------------------------------------
// ONE cooperative kernel, grid=256 x 1024 threads (1 block/CU, 16 waves,
// 4 waves/SIMD). Phases separated by grid.sync():
//  P0: convert disFtr fp32 -> disB bf16 (first 64 blocks, 4 elems/thread).
//      A-chunk0 global loads are issued BEFORE the sync so their HBM latency
//      hides under the sync + other blocks' P0 work.
//  P1: simMax[i][c] = max_p imFtr[i] . disB[c]   (R7 structure, proven exact:
//      wave w owns 64p x 16c; B rolling 8-deep register window; A in 4
//      double-buffered 256-k LDS chunks, XOR-swizzled, 1 barrier/chunk).
//  P2: per-row loss partials {mask count, loss_it, loss_ti}.
//  P3: block 0 reduces 256 partials -> loss scalar.
// Rationale (R7 post-mortem): simmax ~25us = ~344 TF effective for an
// 8.6 GFLOP K-deep GEMM -- above the m97-curve for this size; remaining
// recoverable time is launch gaps (4 serial graph nodes -> 1).
// ---------------------------------------------------------------------------
__global__ __launch_bounds__(1024, 4) void fused_kernel(
    const float* __restrict__ imFtr, const float* __restrict__ disFtr,
    const int* __restrict__ lbl, float* __restrict__ out,
    short* __restrict__ disB, float* __restrict__ simMax,
    float* __restrict__ partial) {
  cg::grid_group grid = cg::this_grid();

  const int i  = blockIdx.x;
  const int t  = threadIdx.x;
  const int w  = t >> 6;   // wave 0..15
  const int l  = t & 63;
  const int lr = l & 15;   // tile col (B,D) / within-tile row (A)
  const int lk = l >> 4;   // k-group 0..3

  __shared__ short Asl[2][NP][256];  // 64 KB: double-buffered A k-chunk (bf16)
  __shared__ float red_sh[3][4];
  __shared__ float posi_sh;

  // --- A staging mapping: thread t -> row ar (0..63), col-group aj (0..15) ---
  const int ar = t >> 4;
  const int aj = t & 15;
  const float* abase = imFtr + ((size_t)i * NP + ar) * ND + aj * 4;
  float4 areg[4];

#define STAGE_LOAD(C)                                                        \
  _Pragma("unroll")                                                          \
  for (int g = 0; g < 4; ++g)                                                \
    areg[g] = *reinterpret_cast<const float4*>(abase + (C) * 256 + g * 64);

#define STAGE_WRITE(BUF)                                                     \
  _Pragma("unroll")                                                          \
  for (int g = 0; g < 4; ++g) {                                              \
    const int s  = g * 8 + (aj >> 1);                                        \
    const int so = (s ^ (ar & 15)) * 8 + (aj & 1) * 4;                       \
    *reinterpret_cast<bf16x4*>(&Asl[BUF][ar][so]) = cvt4(areg[g]);           \
  }

  // ---- Phase 0: convert disB; overlap A chunk-0 loads with it ----
  STAGE_LOAD(0);  // in flight across the grid sync
  {
    const int gid = i * 1024 + t;           // 262144 floats / 4 = 65536 threads
    if (gid < (NB * ND) / 4) {
      const int idx = gid * 4;
      float4 v = *reinterpret_cast<const float4*>(disFtr + idx);
      *reinterpret_cast<bf16x4*>(disB + idx) = cvt4(v);
    }
  }
  grid.sync();

  // ---- Phase 1: simmax ----
  {
    f32x4 acc[4];
#pragma unroll
    for (int pt = 0; pt < 4; ++pt)
#pragma unroll
      for (int r = 0; r < 4; ++r) acc[pt][r] = 0.0f;

    // B: wave col w*16+lr, k-offset lk*8; rolling 8-deep register window
    const short* bp = disB + (size_t)(w * 16 + lr) * ND + lk * 8;
    bf16x8 breg[8];
#pragma unroll
    for (int j = 0; j < 8; ++j)
      breg[j] = *reinterpret_cast<const bf16x8*>(bp + j * 32);

    STAGE_WRITE(0);
    __syncthreads();

#pragma unroll
    for (int c = 0; c < 4; ++c) {
      const int cb = c & 1;
      if (c < 3) STAGE_LOAD(c + 1);  // next A chunk: ~full chunk of lead
#pragma unroll
      for (int j8 = 0; j8 < 8; ++j8) {
        const int jj = c * 8 + j8;          // global 32-k iter (compile-time)
        const int so = ((j8 * 4 + lk) ^ lr) * 8;
        bf16x8 a0 = *reinterpret_cast<const bf16x8*>(&Asl[cb][lr][so]);
        bf16x8 a1 = *reinterpret_cast<const bf16x8*>(&Asl[cb][16 + lr][so]);
        bf16x8 a2 = *reinterpret_cast<const bf16x8*>(&Asl[cb][32 + lr][so]);
        bf16x8 a3 = *reinterpret_cast<const bf16x8*>(&Asl[cb][48 + lr][so]);
        acc[0] = __builtin_amdgcn_mfma_f32_16x16x32_bf16(a0, breg[j8], acc[0], 0, 0, 0);
        acc[1] = __builtin_amdgcn_mfma_f32_16x16x32_bf16(a1, breg[j8], acc[1], 0, 0, 0);
        acc[2] = __builtin_amdgcn_mfma_f32_16x16x32_bf16(a2, breg[j8], acc[2], 0, 0, 0);
        acc[3] = __builtin_amdgcn_mfma_f32_16x16x32_bf16(a3, breg[j8], acc[3], 0, 0, 0);
        if (jj + 8 < 32)                     // refill window 8 iters ahead
          breg[j8] = *reinterpret_cast<const bf16x8*>(bp + (jj + 8) * 32);
      }
      if (c < 3) {
        STAGE_WRITE(cb ^ 1);  // other buffer; readers synced at prior barrier
        __syncthreads();
      }
    }

    // max over all 64 p for this lane's column
    float m = acc[0][0];
#pragma unroll
    for (int pt = 0; pt < 4; ++pt)
#pragma unroll
      for (int r = 0; r < 4; ++r) m = fmaxf(m, acc[pt][r]);
    m = fmaxf(m, __shfl_xor(m, 16));
    m = fmaxf(m, __shfl_xor(m, 32));
    if (l < 16) simMax[(size_t)i * NB + w * 16 + lr] = m;
  }
#undef STAGE_LOAD
#undef STAGE_WRITE
  grid.sync();

  // ---- Phase 2: per-row loss partials (row i = blockIdx, threads 0..255) ----
  {
    const int j = t;
    float s = 0.0f, posj = 0.0f, msk = 0.0f;
    if (j < NB) {
      s = simMax[(size_t)i * NB + j];
      if (j == i) posi_sh = s;
      posj = simMax[(size_t)j * NB + j];
      msk = (lbl[i] != lbl[j]) ? 1.0f : 0.0f;
    }
    __syncthreads();
    float c = 0.0f, l1 = 0.0f, l2 = 0.0f;
    if (j < NB) {
      const float posi = posi_sh;
      c  = msk;
      l1 = msk * fmaxf(s - posi + MARGIN, 0.0f);
      l2 = msk * fmaxf(s - posj + MARGIN, 0.0f);
    }
#pragma unroll
    for (int o = 32; o > 0; o >>= 1) {
      c  += __shfl_down(c, o);
      l1 += __shfl_down(l1, o);
      l2 += __shfl_down(l2, o);
    }
    if (j < NB && (j & 63) == 0) {
      red_sh[0][j >> 6] = c; red_sh[1][j >> 6] = l1; red_sh[2][j >> 6] = l2;
    }
    __syncthreads();
    if (j == 0) {
      partial[i * 3 + 0] = red_sh[0][0] + red_sh[0][1] + red_sh[0][2] + red_sh[0][3];
      partial[i * 3 + 1] = red_sh[1][0] + red_sh[1][1] + red_sh[1][2] + red_sh[1][3];
      partial[i * 3 + 2] = red_sh[2][0] + red_sh[2][1] + red_sh[2][2] + red_sh[2][3];
    }
  }
  grid.sync();

  // ---- Phase 3: block 0 reduces 256 partials -> scalar ----
  if (i == 0) {
    float c = 0.0f, l1 = 0.0f, l2 = 0.0f;
    if (t < NB) {
      c  = partial[t * 3 + 0];
      l1 = partial[t * 3 + 1];
      l2 = partial[t * 3 + 2];
    }
#pragma unroll
    for (int o = 32; o > 0; o >>= 1) {
      c  += __shfl_down(c, o);
      l1 += __shfl_down(l1, o);
      l2 += __shfl_down(l2, o);
    }
    if (t < NB && (t & 63) == 0) {
      red_sh[0][t >> 6] = c; red_sh[1][t >> 6] = l1; red_sh[2][t >> 6] = l2;
    }
    __syncthreads();
    if (t == 0) {
      float cs  = red_sh[0][0] + red_sh[0][1] + red_sh[0][2] + red_sh[0][3];
      float l1s = red_sh[1][0] + red_sh[1][1] + red_sh[1][2] + red_sh[1][3];
      float l2s = red_sh[2][0] + red_sh[2][1] + red_sh[2][2] + red_sh[2][3];
      float loss = l1s / cs;                   // reference divides unconditionally
      loss += (cs > 0.0f) ? (l2s / cs) : 0.0f; // guarded second term, as in ref
      out[0] = loss;
    }
  }
}

extern "C" void kernel_launch(void* const* d_in, const int* in_sizes, int n_in,
                              void* d_out, int out_size, void* d_ws, size_t ws_size,
                              hipStream_t stream) {
  (void)in_sizes; (void)n_in; (void)out_size; (void)ws_size;
  const float* imFtr  = (const float*)d_in[0];
  const float* disFtr = (const float*)d_in[1];
  const int*   lbl    = (const int*)d_in[2];
  float* out = (float*)d_out;

  const size_t disB_bytes = (size_t)NB * ND * sizeof(short);      // 512 KB
  const size_t sim_bytes  = (size_t)NB * NB * sizeof(float);      // 256 KB

  short* disB    = (short*)d_ws;
  float* simMax  = (float*)((char*)d_ws + disB_bytes);
  float* partial = (float*)((char*)d_ws + disB_bytes + sim_bytes);

  void* args[] = {(void*)&imFtr, (void*)&disFtr, (void*)&lbl, (void*)&out,
                  (void*)&disB, (void*)&simMax, (void*)&partial};
  hipLaunchCooperativeKernel((const void*)fused_kernel, dim3(NB), dim3(1024),
                             args, 0, stream);
}

// Round 11
// 115.129 us; speedup vs baseline: 1.0719x; 1.0719x over previous
//
#include <hip/hip_runtime.h>

// Problem constants: B=256, P=64, D=1024, MARGIN=0.1
constexpr int NB = 256;
constexpr int NP = 64;
constexpr int ND = 1024;
constexpr float MARGIN = 0.1f;

typedef __attribute__((ext_vector_type(8))) short bf16x8;  // 8 bf16 (4 VGPRs)
typedef __attribute__((ext_vector_type(4))) short bf16x4;  // 4 bf16 (2 VGPRs)
typedef __attribute__((ext_vector_type(4))) float f32x4;   // MFMA accumulator

// fp32 -> bf16 round-to-nearest-even (inputs are finite gaussians; no NaN path)
static __device__ inline unsigned short f2bf(float f) {
  unsigned u = __builtin_bit_cast(unsigned, f);
  u += 0x7fffu + ((u >> 16) & 1u);
  return (unsigned short)(u >> 16);
}

static __device__ inline bf16x4 cvt4(float4 a) {
  bf16x4 r;
  r[0] = (short)f2bf(a.x); r[1] = (short)f2bf(a.y);
  r[2] = (short)f2bf(a.z); r[3] = (short)f2bf(a.w);
  return r;
}

// ---------------------------------------------------------------------------
// Kernel 0: disFtr fp32 -> bf16 + per-launch ticket reset.
// atomicExch (device coherence point) + stream ordering => simmax kernel
// always starts with ticket==0. This makes winner==LAST-block exact.
// (R10 bug: monotonic ticket with poisoned start 0xAAAAAAAA ≡ 170 mod 256
//  fired the "winner" on the 86th arrival -> read 170 unwritten rows.)
// ---------------------------------------------------------------------------
__global__ __launch_bounds__(256) void cvtB_kernel(
    const float* __restrict__ src, short* __restrict__ dst,
    unsigned* __restrict__ ticket) {
  if (blockIdx.x == 0 && threadIdx.x == 0) atomicExch(ticket, 0u);
  const int idx = (blockIdx.x * 256 + threadIdx.x) * 4;
  float4 v = *reinterpret_cast<const float4*>(src + idx);
  *reinterpret_cast<bf16x4*>(dst + idx) = cvt4(v);
}

// ---------------------------------------------------------------------------
// Kernel 1 (R11 = R10 + correct ticket): R7 simmax (proven) + last-block tail.
// grid=256 (1 block/CU), 1024 threads = 16 waves = 4 waves/SIMD.
// simmax: wave w owns all 64 p x 16 c-cols [w*16,w*16+16); B rolling 8-deep
// register window (static indices); A in 4 double-buffered 256-k LDS chunks,
// XOR-swizzled, 1 barrier/chunk.
// Tail (threadFenceReduction pattern):
//   simMax stores -> __syncthreads() (drains whole block's stores) ->
//   __threadfence() (device release) -> atomicAdd ticket; winner old==255
//   (strictly last) -> __threadfence() (acquire) -> fixed-order loss
//   reduction (winner-independent fp32 order => deterministic output).
// ---------------------------------------------------------------------------
__global__ __launch_bounds__(1024, 4) void simmax_loss_kernel(
    const float* __restrict__ imFtr, const short* __restrict__ disB,
    const int* __restrict__ lbl, float* __restrict__ out,
    float* __restrict__ simMax, unsigned* __restrict__ ticket) {
  const int i  = blockIdx.x;
  const int t  = threadIdx.x;
  const int w  = t >> 6;   // wave 0..15
  const int l  = t & 63;
  const int lr = l & 15;   // tile col (B,D) / within-tile row (A)
  const int lk = l >> 4;   // k-group 0..3

  __shared__ short Asl[2][NP][256];  // 64 KB: double-buffered A k-chunk (bf16)
  __shared__ float diag_sh[NB];
  __shared__ int   lbl_sh[NB];
  __shared__ float fred[3][16];
  __shared__ int   winner_sh;

  // --- A staging mapping: thread t -> row ar (0..63), col-group aj (0..15) ---
  const int ar = t >> 4;
  const int aj = t & 15;
  const float* abase = imFtr + ((size_t)i * NP + ar) * ND + aj * 4;
  float4 areg[4];

#define STAGE_LOAD(C)                                                        \
  _Pragma("unroll")                                                          \
  for (int g = 0; g < 4; ++g)                                                \
    areg[g] = *reinterpret_cast<const float4*>(abase + (C) * 256 + g * 64);

#define STAGE_WRITE(BUF)                                                     \
  _Pragma("unroll")                                                          \
  for (int g = 0; g < 4; ++g) {                                              \
    const int s  = g * 8 + (aj >> 1);                                        \
    const int so = (s ^ (ar & 15)) * 8 + (aj & 1) * 4;                       \
    *reinterpret_cast<bf16x4*>(&Asl[BUF][ar][so]) = cvt4(areg[g]);           \
  }

  // ---- simmax phase (R7 verbatim) ----
  {
    f32x4 acc[4];
#pragma unroll
    for (int pt = 0; pt < 4; ++pt)
#pragma unroll
      for (int r = 0; r < 4; ++r) acc[pt][r] = 0.0f;

    STAGE_LOAD(0);
    // B: wave col w*16+lr, k-offset lk*8; rolling 8-deep register window
    const short* bp = disB + (size_t)(w * 16 + lr) * ND + lk * 8;
    bf16x8 breg[8];
#pragma unroll
    for (int j = 0; j < 8; ++j)
      breg[j] = *reinterpret_cast<const bf16x8*>(bp + j * 32);

    STAGE_WRITE(0);
    __syncthreads();

#pragma unroll
    for (int c = 0; c < 4; ++c) {
      const int cb = c & 1;
      if (c < 3) STAGE_LOAD(c + 1);  // next A chunk: ~full chunk of lead
#pragma unroll
      for (int j8 = 0; j8 < 8; ++j8) {
        const int jj = c * 8 + j8;          // global 32-k iter (compile-time)
        const int so = ((j8 * 4 + lk) ^ lr) * 8;
        bf16x8 a0 = *reinterpret_cast<const bf16x8*>(&Asl[cb][lr][so]);
        bf16x8 a1 = *reinterpret_cast<const bf16x8*>(&Asl[cb][16 + lr][so]);
        bf16x8 a2 = *reinterpret_cast<const bf16x8*>(&Asl[cb][32 + lr][so]);
        bf16x8 a3 = *reinterpret_cast<const bf16x8*>(&Asl[cb][48 + lr][so]);
        acc[0] = __builtin_amdgcn_mfma_f32_16x16x32_bf16(a0, breg[j8], acc[0], 0, 0, 0);
        acc[1] = __builtin_amdgcn_mfma_f32_16x16x32_bf16(a1, breg[j8], acc[1], 0, 0, 0);
        acc[2] = __builtin_amdgcn_mfma_f32_16x16x32_bf16(a2, breg[j8], acc[2], 0, 0, 0);
        acc[3] = __builtin_amdgcn_mfma_f32_16x16x32_bf16(a3, breg[j8], acc[3], 0, 0, 0);
        if (jj + 8 < 32)                     // refill window 8 iters ahead
          breg[j8] = *reinterpret_cast<const bf16x8*>(bp + (jj + 8) * 32);
      }
      if (c < 3) {
        STAGE_WRITE(cb ^ 1);  // other buffer; readers synced at prior barrier
        __syncthreads();
      }
    }

    // max over all 64 p for this lane's column
    float m = acc[0][0];
#pragma unroll
    for (int pt = 0; pt < 4; ++pt)
#pragma unroll
      for (int r = 0; r < 4; ++r) m = fmaxf(m, acc[pt][r]);
    m = fmaxf(m, __shfl_xor(m, 16));
    m = fmaxf(m, __shfl_xor(m, 32));
    if (l < 16) simMax[(size_t)i * NB + w * 16 + lr] = m;
  }
#undef STAGE_LOAD
#undef STAGE_WRITE

  // ---- ticket: STRICTLY-LAST block computes the loss ----
  __syncthreads();                 // whole block's simMax stores issued+drained
  __threadfence();                 // device-scope release of simMax stores
  if (t == 0) {
    unsigned old = atomicAdd(ticket, 1u);
    winner_sh = (old == 255u) ? 1 : 0;   // exact: ticket reset to 0 in cvtB
  }
  __syncthreads();
  if (!winner_sh) return;
  __threadfence();                 // acquire: see all blocks' simMax stores

  // cache diag + labels in LDS
  if (t < NB) {
    diag_sh[t] = simMax[(size_t)t * NB + t];
    lbl_sh[t]  = lbl[t];
  }
  __syncthreads();

  // 65536 pairs / 1024 threads = 64 pairs each; fixed-order sums
  // (independent of which block wins -> bitwise deterministic).
  float c = 0.0f, l1 = 0.0f, l2 = 0.0f;
#pragma unroll
  for (int k = 0; k < 64; ++k) {
    const int idx = t + (k << 10);
    const int ii  = idx >> 8;
    const int jj  = idx & 255;
    const float s = simMax[idx];
    if (lbl_sh[ii] != lbl_sh[jj]) {
      c  += 1.0f;
      l1 += fmaxf(s - diag_sh[ii] + MARGIN, 0.0f);
      l2 += fmaxf(s - diag_sh[jj] + MARGIN, 0.0f);
    }
  }
#pragma unroll
  for (int o = 32; o > 0; o >>= 1) {
    c  += __shfl_down(c, o);
    l1 += __shfl_down(l1, o);
    l2 += __shfl_down(l2, o);
  }
  if (l == 0) { fred[0][w] = c; fred[1][w] = l1; fred[2][w] = l2; }
  __syncthreads();
  if (t == 0) {
    float cs = 0.0f, l1s = 0.0f, l2s = 0.0f;
#pragma unroll
    for (int q = 0; q < 16; ++q) { cs += fred[0][q]; l1s += fred[1][q]; l2s += fred[2][q]; }
    float loss = l1s / cs;                   // reference divides unconditionally
    loss += (cs > 0.0f) ? (l2s / cs) : 0.0f; // guarded second term, as in ref
    out[0] = loss;
  }
}

extern "C" void kernel_launch(void* const* d_in, const int* in_sizes, int n_in,
                              void* d_out, int out_size, void* d_ws, size_t ws_size,
                              hipStream_t stream) {
  (void)in_sizes; (void)n_in; (void)out_size; (void)ws_size;
  const float* imFtr  = (const float*)d_in[0];
  const float* disFtr = (const float*)d_in[1];
  const int*   lbl    = (const int*)d_in[2];
  float* out = (float*)d_out;

  const size_t disB_bytes = (size_t)NB * ND * sizeof(short);      // 512 KB
  const size_t sim_bytes  = (size_t)NB * NB * sizeof(float);      // 256 KB

  short*    disB   = (short*)d_ws;
  float*    simMax = (float*)((char*)d_ws + disB_bytes);
  unsigned* ticket = (unsigned*)((char*)d_ws + disB_bytes + sim_bytes);

  cvtB_kernel<<<dim3(NB), dim3(256), 0, stream>>>(disFtr, disB, ticket);
  simmax_loss_kernel<<<dim3(NB), dim3(1024), 0, stream>>>(
      imFtr, disB, lbl, out, simMax, ticket);
}

// Round 12
// 57.609 us; speedup vs baseline: 2.1422x; 1.9985x over previous
//
#include <hip/hip_runtime.h>

// Problem constants: B=256, P=64, D=1024, MARGIN=0.1
constexpr int NB = 256;
constexpr int NP = 64;
constexpr int ND = 1024;
constexpr float MARGIN = 0.1f;

typedef __attribute__((ext_vector_type(8))) short bf16x8;  // 8 bf16 (4 VGPRs)
typedef __attribute__((ext_vector_type(4))) short bf16x4;  // 4 bf16 (2 VGPRs)
typedef __attribute__((ext_vector_type(4))) float f32x4;   // MFMA accumulator

// fp32 -> bf16 round-to-nearest-even (inputs are finite gaussians; no NaN path)
static __device__ inline unsigned short f2bf(float f) {
  unsigned u = __builtin_bit_cast(unsigned, f);
  u += 0x7fffu + ((u >> 16) & 1u);
  return (unsigned short)(u >> 16);
}

static __device__ inline bf16x4 cvt4(float4 a) {
  bf16x4 r;
  r[0] = (short)f2bf(a.x); r[1] = (short)f2bf(a.y);
  r[2] = (short)f2bf(a.z); r[3] = (short)f2bf(a.w);
  return r;
}

// ---------------------------------------------------------------------------
// Kernel 0: disFtr fp32 -> bf16 + per-launch ticket reset (R11 fix, kept).
// ---------------------------------------------------------------------------
__global__ __launch_bounds__(256) void cvtB_kernel(
    const float* __restrict__ src, short* __restrict__ dst,
    unsigned* __restrict__ ticket) {
  if (blockIdx.x == 0 && threadIdx.x == 0) atomicExch(ticket, 0u);
  const int idx = (blockIdx.x * 256 + threadIdx.x) * 4;
  float4 v = *reinterpret_cast<const float4*>(src + idx);
  *reinterpret_cast<bf16x4*>(dst + idx) = cvt4(v);
}

// ---------------------------------------------------------------------------
// Kernel 1 (R12): R7 simmax (proven) + last-block loss tail with
// MINIMAL-SEMANTICS synchronization.
// R11 post-mortem: __threadfence() by all 1024 threads/block = agent-scope
// full fence (buffer_wbl2 + buffer_inv) per wave -> staggered finishing
// blocks invalidated their XCD's L2 all run long -> still-running blocks'
// disB refills became HBM-latency misses (150us, all pipes idle). Same
// mechanism explains R8's grid.sync 113us.
// Fix: release = __hip_atomic_fetch_add(RELEASE, AGENT) in thread 0 only
// (wbl2 only, NO invalidate, 1 per block); acquire = ONE
// __hip_atomic_load(ACQUIRE, AGENT) in the winner (single buffer_inv in the
// whole grid, after all compute). Block stores are already vmcnt-drained
// into L2 by the preceding __syncthreads, so the release publishes the
// whole block's rows (barrier ordering gives transitive happens-before).
// ---------------------------------------------------------------------------
__global__ __launch_bounds__(1024, 4) void simmax_loss_kernel(
    const float* __restrict__ imFtr, const short* __restrict__ disB,
    const int* __restrict__ lbl, float* __restrict__ out,
    float* __restrict__ simMax, unsigned* __restrict__ ticket) {
  const int i  = blockIdx.x;
  const int t  = threadIdx.x;
  const int w  = t >> 6;   // wave 0..15
  const int l  = t & 63;
  const int lr = l & 15;   // tile col (B,D) / within-tile row (A)
  const int lk = l >> 4;   // k-group 0..3

  __shared__ short Asl[2][NP][256];  // 64 KB: double-buffered A k-chunk (bf16)
  __shared__ float diag_sh[NB];
  __shared__ int   lbl_sh[NB];
  __shared__ float fred[3][16];
  __shared__ int   winner_sh;

  // --- A staging mapping: thread t -> row ar (0..63), col-group aj (0..15) ---
  const int ar = t >> 4;
  const int aj = t & 15;
  const float* abase = imFtr + ((size_t)i * NP + ar) * ND + aj * 4;
  float4 areg[4];

#define STAGE_LOAD(C)                                                        \
  _Pragma("unroll")                                                          \
  for (int g = 0; g < 4; ++g)                                                \
    areg[g] = *reinterpret_cast<const float4*>(abase + (C) * 256 + g * 64);

#define STAGE_WRITE(BUF)                                                     \
  _Pragma("unroll")                                                          \
  for (int g = 0; g < 4; ++g) {                                              \
    const int s  = g * 8 + (aj >> 1);                                        \
    const int so = (s ^ (ar & 15)) * 8 + (aj & 1) * 4;                       \
    *reinterpret_cast<bf16x4*>(&Asl[BUF][ar][so]) = cvt4(areg[g]);           \
  }

  // ---- simmax phase (R7 verbatim) ----
  {
    f32x4 acc[4];
#pragma unroll
    for (int pt = 0; pt < 4; ++pt)
#pragma unroll
      for (int r = 0; r < 4; ++r) acc[pt][r] = 0.0f;

    STAGE_LOAD(0);
    // B: wave col w*16+lr, k-offset lk*8; rolling 8-deep register window
    const short* bp = disB + (size_t)(w * 16 + lr) * ND + lk * 8;
    bf16x8 breg[8];
#pragma unroll
    for (int j = 0; j < 8; ++j)
      breg[j] = *reinterpret_cast<const bf16x8*>(bp + j * 32);

    STAGE_WRITE(0);
    __syncthreads();

#pragma unroll
    for (int c = 0; c < 4; ++c) {
      const int cb = c & 1;
      if (c < 3) STAGE_LOAD(c + 1);  // next A chunk: ~full chunk of lead
#pragma unroll
      for (int j8 = 0; j8 < 8; ++j8) {
        const int jj = c * 8 + j8;          // global 32-k iter (compile-time)
        const int so = ((j8 * 4 + lk) ^ lr) * 8;
        bf16x8 a0 = *reinterpret_cast<const bf16x8*>(&Asl[cb][lr][so]);
        bf16x8 a1 = *reinterpret_cast<const bf16x8*>(&Asl[cb][16 + lr][so]);
        bf16x8 a2 = *reinterpret_cast<const bf16x8*>(&Asl[cb][32 + lr][so]);
        bf16x8 a3 = *reinterpret_cast<const bf16x8*>(&Asl[cb][48 + lr][so]);
        acc[0] = __builtin_amdgcn_mfma_f32_16x16x32_bf16(a0, breg[j8], acc[0], 0, 0, 0);
        acc[1] = __builtin_amdgcn_mfma_f32_16x16x32_bf16(a1, breg[j8], acc[1], 0, 0, 0);
        acc[2] = __builtin_amdgcn_mfma_f32_16x16x32_bf16(a2, breg[j8], acc[2], 0, 0, 0);
        acc[3] = __builtin_amdgcn_mfma_f32_16x16x32_bf16(a3, breg[j8], acc[3], 0, 0, 0);
        if (jj + 8 < 32)                     // refill window 8 iters ahead
          breg[j8] = *reinterpret_cast<const bf16x8*>(bp + (jj + 8) * 32);
      }
      if (c < 3) {
        STAGE_WRITE(cb ^ 1);  // other buffer; readers synced at prior barrier
        __syncthreads();
      }
    }

    // max over all 64 p for this lane's column
    float m = acc[0][0];
#pragma unroll
    for (int pt = 0; pt < 4; ++pt)
#pragma unroll
      for (int r = 0; r < 4; ++r) m = fmaxf(m, acc[pt][r]);
    m = fmaxf(m, __shfl_xor(m, 16));
    m = fmaxf(m, __shfl_xor(m, 32));
    if (l < 16) simMax[(size_t)i * NB + w * 16 + lr] = m;
  }
#undef STAGE_LOAD
#undef STAGE_WRITE

  // ---- ticket: STRICTLY-LAST block computes the loss ----
  __syncthreads();   // all 16 waves' simMax stores vmcnt-drained (into L2)
  if (t == 0) {
    // release: wbl2 only (publish this XCD's dirty lines), no L2 invalidate
    unsigned old = __hip_atomic_fetch_add(ticket, 1u, __ATOMIC_RELEASE,
                                          __HIP_MEMORY_SCOPE_AGENT);
    winner_sh = (old == 255u) ? 1 : 0;   // exact: ticket reset to 0 in cvtB
  }
  __syncthreads();
  if (!winner_sh) return;

  // acquire: single buffer_inv in the whole grid, after all compute is done
  if (t == 0)
    (void)__hip_atomic_load(ticket, __ATOMIC_ACQUIRE, __HIP_MEMORY_SCOPE_AGENT);
  __syncthreads();

  // cache diag + labels in LDS
  if (t < NB) {
    diag_sh[t] = simMax[(size_t)t * NB + t];
    lbl_sh[t]  = lbl[t];
  }
  __syncthreads();

  // 65536 pairs / 1024 threads = 64 pairs each; fixed-order sums
  // (independent of which block wins -> bitwise deterministic).
  float c = 0.0f, l1 = 0.0f, l2 = 0.0f;
#pragma unroll
  for (int k = 0; k < 64; ++k) {
    const int idx = t + (k << 10);
    const int ii  = idx >> 8;
    const int jj  = idx & 255;
    const float s = simMax[idx];
    if (lbl_sh[ii] != lbl_sh[jj]) {
      c  += 1.0f;
      l1 += fmaxf(s - diag_sh[ii] + MARGIN, 0.0f);
      l2 += fmaxf(s - diag_sh[jj] + MARGIN, 0.0f);
    }
  }
#pragma unroll
  for (int o = 32; o > 0; o >>= 1) {
    c  += __shfl_down(c, o);
    l1 += __shfl_down(l1, o);
    l2 += __shfl_down(l2, o);
  }
  if (l == 0) { fred[0][w] = c; fred[1][w] = l1; fred[2][w] = l2; }
  __syncthreads();
  if (t == 0) {
    float cs = 0.0f, l1s = 0.0f, l2s = 0.0f;
#pragma unroll
    for (int q = 0; q < 16; ++q) { cs += fred[0][q]; l1s += fred[1][q]; l2s += fred[2][q]; }
    float loss = l1s / cs;                   // reference divides unconditionally
    loss += (cs > 0.0f) ? (l2s / cs) : 0.0f; // guarded second term, as in ref
    out[0] = loss;
  }
}

extern "C" void kernel_launch(void* const* d_in, const int* in_sizes, int n_in,
                              void* d_out, int out_size, void* d_ws, size_t ws_size,
                              hipStream_t stream) {
  (void)in_sizes; (void)n_in; (void)out_size; (void)ws_size;
  const float* imFtr  = (const float*)d_in[0];
  const float* disFtr = (const float*)d_in[1];
  const int*   lbl    = (const int*)d_in[2];
  float* out = (float*)d_out;

  const size_t disB_bytes = (size_t)NB * ND * sizeof(short);      // 512 KB
  const size_t sim_bytes  = (size_t)NB * NB * sizeof(float);      // 256 KB

  short*    disB   = (short*)d_ws;
  float*    simMax = (float*)((char*)d_ws + disB_bytes);
  unsigned* ticket = (unsigned*)((char*)d_ws + disB_bytes + sim_bytes);

  cvtB_kernel<<<dim3(NB), dim3(256), 0, stream>>>(disFtr, disB, ticket);
  simmax_loss_kernel<<<dim3(NB), dim3(1024), 0, stream>>>(
      imFtr, disB, lbl, out, simMax, ticket);
}

// Round 13
// 56.478 us; speedup vs baseline: 2.1851x; 1.0200x over previous
//
#include <hip/hip_runtime.h>

// Problem constants: B=256, P=64, D=1024, MARGIN=0.1
constexpr int NB = 256;
constexpr int NP = 64;
constexpr int ND = 1024;
constexpr float MARGIN = 0.1f;

typedef __attribute__((ext_vector_type(8))) short bf16x8;  // 8 bf16 (4 VGPRs)
typedef __attribute__((ext_vector_type(4))) short bf16x4;  // 4 bf16 (2 VGPRs)
typedef __attribute__((ext_vector_type(4))) float f32x4;   // MFMA accumulator

// fp32 -> bf16 round-to-nearest-even (inputs are finite gaussians; no NaN path)
static __device__ inline unsigned short f2bf(float f) {
  unsigned u = __builtin_bit_cast(unsigned, f);
  u += 0x7fffu + ((u >> 16) & 1u);
  return (unsigned short)(u >> 16);
}

static __device__ inline bf16x4 cvt4(float4 a) {
  bf16x4 r;
  r[0] = (short)f2bf(a.x); r[1] = (short)f2bf(a.y);
  r[2] = (short)f2bf(a.z); r[3] = (short)f2bf(a.w);
  return r;
}

// ---------------------------------------------------------------------------
// Kernel 0: disFtr fp32 -> bf16 + per-launch ticket reset (kept from R11).
// ---------------------------------------------------------------------------
__global__ __launch_bounds__(256) void cvtB_kernel(
    const float* __restrict__ src, short* __restrict__ dst,
    unsigned* __restrict__ ticket) {
  if (blockIdx.x == 0 && threadIdx.x == 0) atomicExch(ticket, 0u);
  const int idx = (blockIdx.x * 256 + threadIdx.x) * 4;
  float4 v = *reinterpret_cast<const float4*>(src + idx);
  *reinterpret_cast<bf16x4*>(dst + idx) = cvt4(v);
}

// ---------------------------------------------------------------------------
// Kernel 1 (R13): R7 simmax (proven) + last-block loss tail, with
// COHERENT DATA instead of cache-maintenance fences.
// R12 post-mortem: per-block RELEASE fetch_add emits buffer_wbl2 (full-L2
// writeback walk); 32 staggered walks per XCD stalled everyone's disB
// refills (58us). R11: full __threadfence per wave = wbl2+inv storm (150us).
// R13: simMax is written with agent-scope RELAXED stores (sc1: write-through
// to the device coherence point; 256 scalar stores/block, trivial) ->
//   release side needs NO cache op: __syncthreads() vmcnt-drains the sc1
//   stores (write-confirm from coherence point), then RELAXED fetch_add.
//   winner side: ONE ACQUIRE atomic load (single buffer_inv in the whole
//   grid, after all compute) -> winner's plain loads see coherent data.
// Winner = strictly-last (old==255; ticket reset each launch). Fixed-order
// reduction -> bitwise-deterministic output regardless of which block wins.
// ---------------------------------------------------------------------------
__global__ __launch_bounds__(1024, 4) void simmax_loss_kernel(
    const float* __restrict__ imFtr, const short* __restrict__ disB,
    const int* __restrict__ lbl, float* __restrict__ out,
    float* __restrict__ simMax, unsigned* __restrict__ ticket) {
  const int i  = blockIdx.x;
  const int t  = threadIdx.x;
  const int w  = t >> 6;   // wave 0..15
  const int l  = t & 63;
  const int lr = l & 15;   // tile col (B,D) / within-tile row (A)
  const int lk = l >> 4;   // k-group 0..3

  __shared__ short Asl[2][NP][256];  // 64 KB: double-buffered A k-chunk (bf16)
  __shared__ float diag_sh[NB];
  __shared__ int   lbl_sh[NB];
  __shared__ float fred[3][16];
  __shared__ int   winner_sh;

  // --- A staging mapping: thread t -> row ar (0..63), col-group aj (0..15) ---
  const int ar = t >> 4;
  const int aj = t & 15;
  const float* abase = imFtr + ((size_t)i * NP + ar) * ND + aj * 4;
  float4 areg[4];

#define STAGE_LOAD(C)                                                        \
  _Pragma("unroll")                                                          \
  for (int g = 0; g < 4; ++g)                                                \
    areg[g] = *reinterpret_cast<const float4*>(abase + (C) * 256 + g * 64);

#define STAGE_WRITE(BUF)                                                     \
  _Pragma("unroll")                                                          \
  for (int g = 0; g < 4; ++g) {                                              \
    const int s  = g * 8 + (aj >> 1);                                        \
    const int so = (s ^ (ar & 15)) * 8 + (aj & 1) * 4;                       \
    *reinterpret_cast<bf16x4*>(&Asl[BUF][ar][so]) = cvt4(areg[g]);           \
  }

  // ---- simmax phase (R7 verbatim) ----
  {
    f32x4 acc[4];
#pragma unroll
    for (int pt = 0; pt < 4; ++pt)
#pragma unroll
      for (int r = 0; r < 4; ++r) acc[pt][r] = 0.0f;

    STAGE_LOAD(0);
    // B: wave col w*16+lr, k-offset lk*8; rolling 8-deep register window
    const short* bp = disB + (size_t)(w * 16 + lr) * ND + lk * 8;
    bf16x8 breg[8];
#pragma unroll
    for (int j = 0; j < 8; ++j)
      breg[j] = *reinterpret_cast<const bf16x8*>(bp + j * 32);

    STAGE_WRITE(0);
    __syncthreads();

#pragma unroll
    for (int c = 0; c < 4; ++c) {
      const int cb = c & 1;
      if (c < 3) STAGE_LOAD(c + 1);  // next A chunk: ~full chunk of lead
#pragma unroll
      for (int j8 = 0; j8 < 8; ++j8) {
        const int jj = c * 8 + j8;          // global 32-k iter (compile-time)
        const int so = ((j8 * 4 + lk) ^ lr) * 8;
        bf16x8 a0 = *reinterpret_cast<const bf16x8*>(&Asl[cb][lr][so]);
        bf16x8 a1 = *reinterpret_cast<const bf16x8*>(&Asl[cb][16 + lr][so]);
        bf16x8 a2 = *reinterpret_cast<const bf16x8*>(&Asl[cb][32 + lr][so]);
        bf16x8 a3 = *reinterpret_cast<const bf16x8*>(&Asl[cb][48 + lr][so]);
        acc[0] = __builtin_amdgcn_mfma_f32_16x16x32_bf16(a0, breg[j8], acc[0], 0, 0, 0);
        acc[1] = __builtin_amdgcn_mfma_f32_16x16x32_bf16(a1, breg[j8], acc[1], 0, 0, 0);
        acc[2] = __builtin_amdgcn_mfma_f32_16x16x32_bf16(a2, breg[j8], acc[2], 0, 0, 0);
        acc[3] = __builtin_amdgcn_mfma_f32_16x16x32_bf16(a3, breg[j8], acc[3], 0, 0, 0);
        if (jj + 8 < 32)                     // refill window 8 iters ahead
          breg[j8] = *reinterpret_cast<const bf16x8*>(bp + (jj + 8) * 32);
      }
      if (c < 3) {
        STAGE_WRITE(cb ^ 1);  // other buffer; readers synced at prior barrier
        __syncthreads();
      }
    }

    // max over all 64 p for this lane's column; store COHERENT (sc1)
    float m = acc[0][0];
#pragma unroll
    for (int pt = 0; pt < 4; ++pt)
#pragma unroll
      for (int r = 0; r < 4; ++r) m = fmaxf(m, acc[pt][r]);
    m = fmaxf(m, __shfl_xor(m, 16));
    m = fmaxf(m, __shfl_xor(m, 32));
    if (l < 16)
      __hip_atomic_store(&simMax[(size_t)i * NB + w * 16 + lr], m,
                         __ATOMIC_RELAXED, __HIP_MEMORY_SCOPE_AGENT);
  }
#undef STAGE_LOAD
#undef STAGE_WRITE

  // ---- ticket: STRICTLY-LAST block computes the loss ----
  __syncthreads();   // vmcnt-drain: all 16 waves' sc1 stores confirmed at the
                     // device coherence point before thread 0 increments
  if (t == 0) {
    unsigned old = __hip_atomic_fetch_add(ticket, 1u, __ATOMIC_RELAXED,
                                          __HIP_MEMORY_SCOPE_AGENT);
    winner_sh = (old == 255u) ? 1 : 0;   // exact: ticket reset to 0 in cvtB
  }
  __syncthreads();
  if (!winner_sh) return;

  // acquire: single buffer_inv in the whole grid, after all compute is done
  if (t == 0)
    (void)__hip_atomic_load(ticket, __ATOMIC_ACQUIRE, __HIP_MEMORY_SCOPE_AGENT);
  __syncthreads();

  // cache diag + labels in LDS
  if (t < NB) {
    diag_sh[t] = simMax[(size_t)t * NB + t];
    lbl_sh[t]  = lbl[t];
  }
  __syncthreads();

  // 65536 pairs / 1024 threads = 64 pairs each; fixed-order sums
  float c = 0.0f, l1 = 0.0f, l2 = 0.0f;
#pragma unroll
  for (int k = 0; k < 64; ++k) {
    const int idx = t + (k << 10);
    const int ii  = idx >> 8;
    const int jj  = idx & 255;
    const float s = simMax[idx];
    if (lbl_sh[ii] != lbl_sh[jj]) {
      c  += 1.0f;
      l1 += fmaxf(s - diag_sh[ii] + MARGIN, 0.0f);
      l2 += fmaxf(s - diag_sh[jj] + MARGIN, 0.0f);
    }
  }
#pragma unroll
  for (int o = 32; o > 0; o >>= 1) {
    c  += __shfl_down(c, o);
    l1 += __shfl_down(l1, o);
    l2 += __shfl_down(l2, o);
  }
  if (l == 0) { fred[0][w] = c; fred[1][w] = l1; fred[2][w] = l2; }
  __syncthreads();
  if (t == 0) {
    float cs = 0.0f, l1s = 0.0f, l2s = 0.0f;
#pragma unroll
    for (int q = 0; q < 16; ++q) { cs += fred[0][q]; l1s += fred[1][q]; l2s += fred[2][q]; }
    float loss = l1s / cs;                   // reference divides unconditionally
    loss += (cs > 0.0f) ? (l2s / cs) : 0.0f; // guarded second term, as in ref
    out[0] = loss;
  }
}

extern "C" void kernel_launch(void* const* d_in, const int* in_sizes, int n_in,
                              void* d_out, int out_size, void* d_ws, size_t ws_size,
                              hipStream_t stream) {
  (void)in_sizes; (void)n_in; (void)out_size; (void)ws_size;
  const float* imFtr  = (const float*)d_in[0];
  const float* disFtr = (const float*)d_in[1];
  const int*   lbl    = (const int*)d_in[2];
  float* out = (float*)d_out;

  const size_t disB_bytes = (size_t)NB * ND * sizeof(short);      // 512 KB
  const size_t sim_bytes  = (size_t)NB * NB * sizeof(float);      // 256 KB

  short*    disB   = (short*)d_ws;
  float*    simMax = (float*)((char*)d_ws + disB_bytes);
  unsigned* ticket = (unsigned*)((char*)d_ws + disB_bytes + sim_bytes);

  cvtB_kernel<<<dim3(NB), dim3(256), 0, stream>>>(disFtr, disB, ticket);
  simmax_loss_kernel<<<dim3(NB), dim3(1024), 0, stream>>>(
      imFtr, disB, lbl, out, simMax, ticket);
}

// Round 14
// 36.583 us; speedup vs baseline: 3.3735x; 1.5439x over previous
//
#include <hip/hip_runtime.h>

// Problem constants: B=256, P=64, D=1024, MARGIN=0.1
constexpr int NB = 256;
constexpr int NP = 64;
constexpr int ND = 1024;
constexpr float MARGIN = 0.1f;

typedef __attribute__((ext_vector_type(8))) short bf16x8;  // 8 bf16 (4 VGPRs)
typedef __attribute__((ext_vector_type(4))) short bf16x4;  // 4 bf16 (2 VGPRs)
typedef __attribute__((ext_vector_type(4))) float f32x4;   // MFMA accumulator

// fp32 -> bf16 round-to-nearest-even (inputs are finite gaussians; no NaN path)
static __device__ inline unsigned short f2bf(float f) {
  unsigned u = __builtin_bit_cast(unsigned, f);
  u += 0x7fffu + ((u >> 16) & 1u);
  return (unsigned short)(u >> 16);
}

static __device__ inline bf16x4 cvt4(float4 a) {
  bf16x4 r;
  r[0] = (short)f2bf(a.x); r[1] = (short)f2bf(a.y);
  r[2] = (short)f2bf(a.z); r[3] = (short)f2bf(a.w);
  return r;
}

// ---------------------------------------------------------------------------
// Kernel 0: disFtr fp32 -> bf16 + per-launch ticket reset.
// ---------------------------------------------------------------------------
__global__ __launch_bounds__(256) void cvtB_kernel(
    const float* __restrict__ src, short* __restrict__ dst,
    unsigned* __restrict__ ticket) {
  if (blockIdx.x == 0 && threadIdx.x == 0) atomicExch(ticket, 0u);
  const int idx = (blockIdx.x * 256 + threadIdx.x) * 4;
  float4 v = *reinterpret_cast<const float4*>(src + idx);
  *reinterpret_cast<bf16x4*>(dst + idx) = cvt4(v);
}

// ---------------------------------------------------------------------------
// Kernel 1: simmax — R7 VERBATIM (proven 34.5us pipeline; plain stores, no
// atomics). grid=256 (1 block/CU), 1024 threads = 16 waves.
// Fusion post-mortem (R8/R11/R12/R13): ANY tail machinery in this kernel
// correlated with ~2x simmax-phase slowdown regardless of fence strategy —
// so this kernel stays untouched.
// ---------------------------------------------------------------------------
__global__ __launch_bounds__(1024, 4) void simmax_kernel(
    const float* __restrict__ imFtr, const short* __restrict__ disB,
    float* __restrict__ simMax) {
  const int i  = blockIdx.x;
  const int t  = threadIdx.x;
  const int w  = t >> 6;   // wave 0..15
  const int l  = t & 63;
  const int lr = l & 15;   // tile col (B,D) / within-tile row (A)
  const int lk = l >> 4;   // k-group 0..3

  __shared__ short Asl[2][NP][256];  // 64 KB: double-buffered A k-chunk (bf16)

  f32x4 acc[4];
#pragma unroll
  for (int pt = 0; pt < 4; ++pt)
#pragma unroll
    for (int r = 0; r < 4; ++r) acc[pt][r] = 0.0f;

  const int ar = t >> 4;
  const int aj = t & 15;
  const float* abase = imFtr + ((size_t)i * NP + ar) * ND + aj * 4;
  float4 areg[4];

  const short* bp = disB + (size_t)(w * 16 + lr) * ND + lk * 8;
  bf16x8 breg[8];

#define STAGE_LOAD(C)                                                        \
  _Pragma("unroll")                                                          \
  for (int g = 0; g < 4; ++g)                                                \
    areg[g] = *reinterpret_cast<const float4*>(abase + (C) * 256 + g * 64);

#define STAGE_WRITE(BUF)                                                     \
  _Pragma("unroll")                                                          \
  for (int g = 0; g < 4; ++g) {                                              \
    const int s  = g * 8 + (aj >> 1);                                        \
    const int so = (s ^ (ar & 15)) * 8 + (aj & 1) * 4;                       \
    *reinterpret_cast<bf16x4*>(&Asl[BUF][ar][so]) = cvt4(areg[g]);           \
  }

  // ---- prologue: A chunk 0 + B window for iters 0..7 ----
  STAGE_LOAD(0);
#pragma unroll
  for (int j = 0; j < 8; ++j)
    breg[j] = *reinterpret_cast<const bf16x8*>(bp + j * 32);
  STAGE_WRITE(0);
  __syncthreads();

#pragma unroll
  for (int c = 0; c < 4; ++c) {
    const int cb = c & 1;
    if (c < 3) STAGE_LOAD(c + 1);  // next A chunk: ~full chunk of lead
#pragma unroll
    for (int j8 = 0; j8 < 8; ++j8) {
      const int jj = c * 8 + j8;          // global 32-k iter (compile-time)
      const int so = ((j8 * 4 + lk) ^ lr) * 8;
      bf16x8 a0 = *reinterpret_cast<const bf16x8*>(&Asl[cb][lr][so]);
      bf16x8 a1 = *reinterpret_cast<const bf16x8*>(&Asl[cb][16 + lr][so]);
      bf16x8 a2 = *reinterpret_cast<const bf16x8*>(&Asl[cb][32 + lr][so]);
      bf16x8 a3 = *reinterpret_cast<const bf16x8*>(&Asl[cb][48 + lr][so]);
      acc[0] = __builtin_amdgcn_mfma_f32_16x16x32_bf16(a0, breg[j8], acc[0], 0, 0, 0);
      acc[1] = __builtin_amdgcn_mfma_f32_16x16x32_bf16(a1, breg[j8], acc[1], 0, 0, 0);
      acc[2] = __builtin_amdgcn_mfma_f32_16x16x32_bf16(a2, breg[j8], acc[2], 0, 0, 0);
      acc[3] = __builtin_amdgcn_mfma_f32_16x16x32_bf16(a3, breg[j8], acc[3], 0, 0, 0);
      if (jj + 8 < 32)                     // refill window 8 iters ahead
        breg[j8] = *reinterpret_cast<const bf16x8*>(bp + (jj + 8) * 32);
    }
    if (c < 3) {
      STAGE_WRITE(cb ^ 1);  // other buffer; readers synced at prior barrier
      __syncthreads();
    }
  }

#undef STAGE_LOAD
#undef STAGE_WRITE

  // ---- epilogue: max over all 64 p for this lane's column ----
  float m = acc[0][0];
#pragma unroll
  for (int pt = 0; pt < 4; ++pt)
#pragma unroll
    for (int r = 0; r < 4; ++r) m = fmaxf(m, acc[pt][r]);
  m = fmaxf(m, __shfl_xor(m, 16));
  m = fmaxf(m, __shfl_xor(m, 32));
  if (l < 16) simMax[(size_t)i * NB + w * 16 + lr] = m;
}

// ---------------------------------------------------------------------------
// Kernel 2 (R14): loss partials + ticket-fused finalize.
// grid=256 x 256. Block i computes row-i partials {count, l_it, l_ti}
// (identical math/order to the proven loss_kernel), publishes them with
// sc1 relaxed agent stores, then the STRICTLY-LAST block (ticket, reset in
// cvtB) does ONE acquire load (single buffer_inv, after all compute) and
// reduces the 256 partials in the exact fixed order of the old
// finalize_kernel -> bitwise-deterministic out[0].
// Bounded risk: this kernel is ~4us; even a 2x tail penalty loses less than
// the launch gap + finalize kernel it removes.
// ---------------------------------------------------------------------------
__global__ __launch_bounds__(256) void loss_tail_kernel(
    const float* __restrict__ simMax, const int* __restrict__ lbl,
    float* __restrict__ partial, float* __restrict__ out,
    unsigned* __restrict__ ticket) {
  const int i = blockIdx.x;
  const int j = threadIdx.x;
  __shared__ float posi_sh;
  __shared__ float red[3][4];
  __shared__ int winner_sh;

  float s = simMax[(size_t)i * NB + j];
  if (j == i) posi_sh = s;
  __syncthreads();
  const float posi = posi_sh;
  const float posj = simMax[(size_t)j * NB + j];

  const float msk = (lbl[i] != lbl[j]) ? 1.0f : 0.0f;
  float c  = msk;
  float l1 = msk * fmaxf(s - posi + MARGIN, 0.0f);
  float l2 = msk * fmaxf(s - posj + MARGIN, 0.0f);
#pragma unroll
  for (int o = 32; o > 0; o >>= 1) {
    c  += __shfl_down(c, o);
    l1 += __shfl_down(l1, o);
    l2 += __shfl_down(l2, o);
  }
  const int w = j >> 6;
  if ((j & 63) == 0) { red[0][w] = c; red[1][w] = l1; red[2][w] = l2; }
  __syncthreads();
  if (j == 0) {
    // publish coherent (sc1, write-through to device coherence point)
    __hip_atomic_store(&partial[i * 3 + 0],
                       red[0][0] + red[0][1] + red[0][2] + red[0][3],
                       __ATOMIC_RELAXED, __HIP_MEMORY_SCOPE_AGENT);
    __hip_atomic_store(&partial[i * 3 + 1],
                       red[1][0] + red[1][1] + red[1][2] + red[1][3],
                       __ATOMIC_RELAXED, __HIP_MEMORY_SCOPE_AGENT);
    __hip_atomic_store(&partial[i * 3 + 2],
                       red[2][0] + red[2][1] + red[2][2] + red[2][3],
                       __ATOMIC_RELAXED, __HIP_MEMORY_SCOPE_AGENT);
  }
  __syncthreads();   // whole block's sc1 stores drained before the ticket
  if (j == 0) {
    unsigned old = __hip_atomic_fetch_add(ticket, 1u, __ATOMIC_RELAXED,
                                          __HIP_MEMORY_SCOPE_AGENT);
    winner_sh = (old == 255u) ? 1 : 0;   // strictly last; ticket reset in cvtB
  }
  __syncthreads();
  if (!winner_sh) return;
  if (j == 0)
    (void)__hip_atomic_load(ticket, __ATOMIC_ACQUIRE, __HIP_MEMORY_SCOPE_AGENT);
  __syncthreads();

  // finalize (exact order of the old finalize_kernel)
  float fc  = partial[j * 3 + 0];
  float fl1 = partial[j * 3 + 1];
  float fl2 = partial[j * 3 + 2];
#pragma unroll
  for (int o = 32; o > 0; o >>= 1) {
    fc  += __shfl_down(fc, o);
    fl1 += __shfl_down(fl1, o);
    fl2 += __shfl_down(fl2, o);
  }
  if ((j & 63) == 0) { red[0][w] = fc; red[1][w] = fl1; red[2][w] = fl2; }
  __syncthreads();
  if (j == 0) {
    float cs  = red[0][0] + red[0][1] + red[0][2] + red[0][3];
    float l1s = red[1][0] + red[1][1] + red[1][2] + red[1][3];
    float l2s = red[2][0] + red[2][1] + red[2][2] + red[2][3];
    float loss = l1s / cs;                   // reference divides unconditionally
    loss += (cs > 0.0f) ? (l2s / cs) : 0.0f; // guarded second term, as in ref
    out[0] = loss;
  }
}

extern "C" void kernel_launch(void* const* d_in, const int* in_sizes, int n_in,
                              void* d_out, int out_size, void* d_ws, size_t ws_size,
                              hipStream_t stream) {
  (void)in_sizes; (void)n_in; (void)out_size; (void)ws_size;
  const float* imFtr  = (const float*)d_in[0];
  const float* disFtr = (const float*)d_in[1];
  const int*   lbl    = (const int*)d_in[2];
  float* out = (float*)d_out;

  const size_t disB_bytes = (size_t)NB * ND * sizeof(short);      // 512 KB
  const size_t sim_bytes  = (size_t)NB * NB * sizeof(float);      // 256 KB
  const size_t par_bytes  = (size_t)NB * 3 * sizeof(float);

  short*    disB    = (short*)d_ws;
  float*    simMax  = (float*)((char*)d_ws + disB_bytes);
  float*    partial = (float*)((char*)d_ws + disB_bytes + sim_bytes);
  unsigned* ticket  = (unsigned*)((char*)d_ws + disB_bytes + sim_bytes + par_bytes);

  cvtB_kernel<<<dim3(NB), dim3(256), 0, stream>>>(disFtr, disB, ticket);
  simmax_kernel<<<dim3(NB), dim3(1024), 0, stream>>>(imFtr, disB, simMax);
  loss_tail_kernel<<<dim3(NB), dim3(256), 0, stream>>>(simMax, lbl, partial, out, ticket);
}